// Round 3
// baseline (98.055 us; speedup 1.0000x reference)
//
#include <hip/hip_runtime.h>

#define SEQ   512
#define BATCH 256

// Uniform-index lane broadcast via v_readlane (index is wave-uniform).
__device__ __forceinline__ float bcast_f(float v, int srcLane) {
    return __int_as_float(__builtin_amdgcn_readlane(__float_as_int(v), srcLane));
}

// gfx950 transcendentals: v_log_f32 is log2, v_exp_f32 is exp2.
__device__ __forceinline__ float fast_log2(float x) { return __builtin_amdgcn_logf(x); }
__device__ __forceinline__ float fast_exp2(float x) { return __builtin_amdgcn_exp2f(x); }

// One wave per batch column. Lane holds rows i = lane + 64*r, r = 0..7.
// Column sweep j = 0..510: when column j is processed, acc of row j already
// equals expm[j] (it only accumulated columns < j). One v_readlane per step
// extracts the next carry -- no LDS, no barriers.
__global__ void __launch_bounds__(64, 1)
act_r_kernel(const float* __restrict__ sp, const float* __restrict__ w,
             float* __restrict__ out) {
    const int b    = blockIdx.x;   // batch column
    const int lane = threadIdx.x;  // 0..63

    const float a   = w[0];
    const float c   = w[1];
    const float s   = w[2];
    const float tau = w[3];
    const float h   = w[4];
    const float scale = 86400.0f * h;

    // Load this batch's 512 timestamps, pre-scaled.
    float x[8];
#pragma unroll
    for (int r = 0; r < 8; ++r)
        x[r] = sp[(lane + (r << 6)) * BATCH + b] * scale;

    float acc[8];
#pragma unroll
    for (int r = 0; r < 8; ++r) acc[r] = 0.0f;

    float expmj = 0.0f;  // expm[0] = exp(-inf) = 0

#pragma unroll
    for (int jr = 0; jr < 8; ++jr) {            // column register-block
        const int jlimit = (jr == 7) ? 63 : 64; // j stops at 510
        for (int jl = 0; jl < jlimit; ++jl) {
            const int j  = (jr << 6) + jl;
            const float sj = bcast_f(x[jr], jl);
            const float pj = -fmaf(c, expmj, a);
            // Rows with i > j live in register rows r >= jr only.
#pragma unroll
            for (int r = jr; r < 8; ++r) {
                float d = fmaxf(x[r] - sj, 1.0f);
                float t = fast_exp2(pj * fast_log2(d));   // v_exp_f32 / v_log_f32
                if (r == jr) t = (lane > jl) ? t : 0.0f;  // mask i <= j
                acc[r] += t;
            }
            // Carry for next step: expm[j+1] = acc of row j+1.
            const int nj = j + 1;
            float src;
            if (jr < 7) src = (jl == 63) ? acc[jr + 1] : acc[jr];
            else        src = acc[7];
            expmj = bcast_f(src, nj & 63);
        }
    }

    // Epilogue: out[i-1, b] = 1/(1 + exp((tau - ln(acc_i))/s))
    //         = 1/(1 + exp2(tau/(s*ln2) - log2(acc_i)/s))
    const float inv_ln2 = 1.4426950408889634f;
    const float k1 = tau / s * inv_ln2;
    const float k2 = 1.0f / s;
#pragma unroll
    for (int r = 0; r < 8; ++r) {
        const int i = lane + (r << 6);
        if (i >= 1) {
            float q = k1 - k2 * fast_log2(acc[r]);
            float e = fast_exp2(q);
            out[(i - 1) * BATCH + b] = 1.0f / (1.0f + e);
        }
    }
}

extern "C" void kernel_launch(void* const* d_in, const int* in_sizes, int n_in,
                              void* d_out, int out_size, void* d_ws, size_t ws_size,
                              hipStream_t stream) {
    const float* sp = (const float*)d_in[0];  // [512, 256, 1] f32
    const float* w  = (const float*)d_in[1];  // [5] f32
    float* out = (float*)d_out;               // [511, 256, 1] f32
    (void)in_sizes; (void)n_in; (void)out_size; (void)d_ws; (void)ws_size;

    act_r_kernel<<<dim3(BATCH), dim3(64), 0, stream>>>(sp, w, out);
}

// Round 4
// 81.030 us; speedup vs baseline: 1.2101x; 1.2101x over previous
//
#include <hip/hip_runtime.h>

#define SEQ   512
#define BATCH 256
#define NH    7   // helper waves (waves 1..7)

// Uniform-index lane broadcast via v_readlane.
__device__ __forceinline__ float bcast_f(float v, int srcLane) {
    return __int_as_float(__builtin_amdgcn_readlane(__float_as_int(v), srcLane));
}
// gfx950: v_log_f32 is log2, v_exp_f32 is exp2.
__device__ __forceinline__ float flog2(float x) { return __builtin_amdgcn_logf(x); }
__device__ __forceinline__ float fexp2(float x) { return __builtin_amdgcn_exp2f(x); }

// One block (512 threads = 8 waves) per batch column.
// Column blocks J = 0..7 (64 cols each). Wave 0: sequential diagonal sweep of
// block J (the only truly serial part). Helpers (waves 1..7): once expm of
// block J-1 is published, apply those 64 columns to row block J ("panel",
// needed by wave 0 at this phase's merge) and then to row blocks J+1..7
// ("deep", overlapped with wave 0's diagonal sweep). Partials live in
// per-helper LDS slices; wave 0 merges 7 values per phase.
//
// Maskless diagonal trick: for lanes i <= jl, d = max(x_i - x_jl, 1) = 1 so
// the term is exp2(p*0) = 1.0 exactly. The carry for step jl is read from
// lane jl BEFORE that lane receives its first contaminating +1 (steps >= jl),
// so the chain is exact; the final value subtracts (64 - lane) once.
__global__ void __launch_bounds__(512, 1)
act_r_kernel(const float* __restrict__ sp, const float* __restrict__ w,
             float* __restrict__ out) {
    __shared__ float x_lds[SEQ];            // pre-scaled timestamps
    __shared__ float expm_lds[SEQ];         // published expm per row
    __shared__ float part_lds[NH][8][64];   // [helper][row block][lane]

    const int b    = blockIdx.x;
    const int tid  = threadIdx.x;
    const int wid  = tid >> 6;
    const int lane = tid & 63;

    const float a   = w[0];
    const float c   = w[1];
    const float s   = w[2];
    const float tau = w[3];
    const float h   = w[4];
    const float scale = 86400.0f * h;

    // Zero helper partials (7*8*64 = 3584 floats / 512 threads = 7 each).
    for (int k = tid; k < NH * 8 * 64; k += 512) ((float*)part_lds)[k] = 0.0f;
    // Stage pre-scaled x.
    x_lds[tid] = sp[tid * BATCH + b] * scale;
    __syncthreads();

    const float inv_ln2 = 1.4426950408889634f;
    const float k1 = tau / s * inv_ln2;
    const float k2 = 1.0f / s;

    for (int J = 0; J < 8; ++J) {
        // ---- phase A: helpers compute the panel (col block J-1 -> row block J)
        if (wid > 0 && J > 0) {
            const float xr = x_lds[(J << 6) + lane];
            float pacc = 0.0f;
            for (int jc = wid - 1; jc < 64; jc += NH) {
                const int j   = ((J - 1) << 6) + jc;
                const float xj = x_lds[j];
                const float pj = -fmaf(c, expm_lds[j], a);
                const float d  = fmaxf(xr - xj, 1.0f);
                pacc += fexp2(pj * flog2(d));
            }
            part_lds[wid - 1][J][lane] += pacc;
        }
        __syncthreads();  // panel partials for row block J ready

        if (wid == 0) {
            // ---- merge all off-diagonal contributions to row block J
            float acc = 0.0f;
#pragma unroll
            for (int hh = 0; hh < NH; ++hh) acc += part_lds[hh][J][lane];

            const float xd = x_lds[(J << 6) + lane];
            // ---- sequential diagonal sweep (maskless)
#pragma unroll
            for (int jl = 0; jl < 64; ++jl) {
                const float em = bcast_f(acc, jl);   // expm[64J+jl], still clean
                const float pj = -fmaf(c, em, a);
                const float sj = bcast_f(xd, jl);
                const float d  = fmaxf(xd - sj, 1.0f);
                acc += fexp2(pj * flog2(d));
            }
            const float clean = acc - (float)(64 - lane);
            expm_lds[(J << 6) + lane] = clean;       // publish for helpers

            // ---- epilogue for this row block
            const int i = (J << 6) + lane;
            if (i >= 1) {
                const float q = k1 - k2 * flog2(clean);
                out[(i - 1) * BATCH + b] = 1.0f / (1.0f + fexp2(q));
            }
        } else if (J > 0) {
            // ---- deep: col block J-1 -> row blocks J+1..7 (overlaps diag)
            for (int R = J + 1; R < 8; ++R) {
                const float xr = x_lds[(R << 6) + lane];
                float pacc = 0.0f;
                for (int jc = wid - 1; jc < 64; jc += NH) {
                    const int j   = ((J - 1) << 6) + jc;
                    const float xj = x_lds[j];
                    const float pj = -fmaf(c, expm_lds[j], a);
                    const float d  = fmaxf(xr - xj, 1.0f);
                    pacc += fexp2(pj * flog2(d));
                }
                part_lds[wid - 1][R][lane] += pacc;
            }
        }
        __syncthreads();  // expm block J published; deep work done
    }
}

extern "C" void kernel_launch(void* const* d_in, const int* in_sizes, int n_in,
                              void* d_out, int out_size, void* d_ws, size_t ws_size,
                              hipStream_t stream) {
    const float* sp = (const float*)d_in[0];  // [512, 256, 1] f32
    const float* w  = (const float*)d_in[1];  // [5] f32
    float* out = (float*)d_out;               // [511, 256, 1] f32
    (void)in_sizes; (void)n_in; (void)out_size; (void)d_ws; (void)ws_size;

    act_r_kernel<<<dim3(BATCH), dim3(512), 0, stream>>>(sp, w, out);
}